// Round 13
// baseline (123.760 us; speedup 1.0000x reference)
//
#include <hip/hip_runtime.h>
#include <cstdint>

typedef unsigned long long u64;
typedef unsigned int u32;

#define NB 4096
#define NW 64            // 64-bit words per mask row
#define MM 20
#define HH 16
#define COND_THRES 0.2f
#define IOU_THRES 0.3f
#define PI_F  3.14159265358979323846f
#define PI4_F 0.78539816339744830962f

#define NTILE 2080       // lower-triangle 64x64 tiles
#define POOLP 3072       // LDS overflow-pool entries

// ---- workspace layout (bytes) ----
#define WS_MASK    32768                       // u64[NB*NW] = 2 MiB
#define WS_BOX9S   (WS_MASK + NB*NW*8)         // float[NB*9]
#define WS_BEVS    (WS_BOX9S + NB*9*4)         // float4[NB]
#define WS_SCORES  (WS_BEVS + NB*16)           // float[NB]
#define WS_LABELS  (WS_SCORES + NB*4)          // int[NB]
#define WS_NBRW    (WS_LABELS + NB*4)          // u64[NB] ext overlap-word bits
#define WS_SUPSTEP (WS_NBRW + NB*8)            // int[NB]
#define WS_CNT     (WS_SUPSTEP + NB*4)         // u32[NB] slot counters (ext words)
#define WS_SLOTW   (WS_CNT + NB*4)             // u64[NB*2] ext cache words
#define WS_SLOTI   (WS_SLOTW + NB*16)          // u32[NB*2] ext cache word indices
#define WS_CSARR   (WS_SLOTI + NB*8)           // u64[NB] self-word below bits

__device__ __forceinline__ u64 sort_key(float s, int i) {
  u32 sb = (s > COND_THRES) ? __float_as_uint(s) : 0u;
  return ((u64)(sb ^ 0xFFFFFFFFu) << 12) | (u64)i;
}

// ---------- K1: fused counting-rank + scatter + BEV (R7-proven body + cnt zero).
__global__ void __launch_bounds__(256) k_prep(const float* __restrict__ scores,
                                              const float* __restrict__ boxes9,
                                              const int* __restrict__ labels,
                                              float* __restrict__ box9s, float4* __restrict__ bevs,
                                              float* __restrict__ scoress, int* __restrict__ labelss,
                                              u64* __restrict__ nbrw, u32* __restrict__ cnt) {
  #pragma clang fp contract(off)
  __shared__ u64 keys[NB];        // 32 KB
  __shared__ u32 part[16][16];
  int tid = threadIdx.x;
  for (int k = tid; k < NB; k += 256) keys[k] = sort_key(scores[k], k);
  __syncthreads();
  int bl = tid & 15;              // box-local 0..15
  int ch = tid >> 4;              // chunk 0..15 (256 keys each)
  u64 ki = keys[blockIdx.x * 16 + bl];
  int c = 0;
  #pragma unroll 16
  for (int t = 0; t < 256; ++t) c += (keys[(ch << 8) + t] < ki) ? 1 : 0;  // LDS broadcast
  part[bl][ch] = (u32)c;
  __syncthreads();
  if (tid < 16) {
    int i = blockIdx.x * 16 + tid;
    int r = 0;
    #pragma unroll
    for (int q = 0; q < 16; ++q) r += (int)part[tid][q];
    nbrw[i] = 0;
    cnt[i] = 0;
    float b[9];
    #pragma unroll
    for (int f = 0; f < 9; ++f) b[f] = boxes9[i * 9 + f];
    #pragma unroll
    for (int f = 0; f < 9; ++f) box9s[r * 9 + f] = b[f];
    float ang = b[6] - floorf(b[6] / PI_F + 0.5f) * PI_F;
    bool sw = fabsf(ang) >= PI4_F;
    float dx = sw ? b[4] : b[3];
    float dy = sw ? b[3] : b[4];
    bevs[r] = make_float4(b[0] - dx * 0.5f, b[1] - dy * 0.5f,
                          b[0] + dx * 0.5f, b[1] + dy * 0.5f);
    scoress[r] = scores[i];
    labelss[r] = labels[i];
  }
}

// ---------- K2: pairwise over-matrix, symmetric-halved, triangular 2080x64 grid
// (R7-proven packing + R11-proven slot/csArr publication, passed refcheck).
__global__ void __launch_bounds__(64) k_mask(const float4* __restrict__ bevs,
                                             const int* __restrict__ labelss,
                                             const float* __restrict__ scoress,
                                             u64* __restrict__ mask,
                                             u64* __restrict__ nbrw,
                                             u32* __restrict__ cnt,
                                             u64* __restrict__ slotW,
                                             u32* __restrict__ slotI,
                                             u64* __restrict__ csArr) {
  #pragma clang fp contract(off)
  __shared__ float4 bj[64];
  __shared__ int lj[64];
  __shared__ u64 tw[64];
  int t = threadIdx.x;
  // triangular decode: largest it with it*(it+1)/2 <= b (float estimate + exact fix)
  int b = blockIdx.x;
  int it = (int)((sqrtf(8.0f * (float)b + 1.0f) - 1.0f) * 0.5f);
  while ((it + 1) * (it + 2) / 2 <= b) ++it;
  while (it * (it + 1) / 2 > b) --it;
  int jt = b - it * (it + 1) / 2;
  int j = jt * 64 + t;
  bj[t] = bevs[j];
  lj[t] = labelss[j];
  u64 vj = __ballot(scoress[j] > COND_THRES);   // valid mask of this j-tile
  int i = it * 64 + t;
  float4 a = bevs[i];
  int la = labelss[i];
  float area_a = (a.z - a.x) * (a.w - a.y);
  __syncthreads();
  u64 w = 0;
  #pragma unroll 8
  for (int kk = 0; kk < 64; ++kk) {
    float4 bb = bj[kk];
    float xmin = fmaxf(a.x, bb.x), ymin = fmaxf(a.y, bb.y);
    float xmax = fminf(a.z, bb.z), ymax = fminf(a.w, bb.w);
    float inter = fmaxf(xmax - xmin, 0.0f) * fmaxf(ymax - ymin, 0.0f);
    float area_b = (bb.z - bb.x) * (bb.w - bb.y);
    float iou = inter / fmaxf(area_a + area_b - inter, 1e-6f);
    if ((iou > IOU_THRES) && (la == lj[kk])) w |= (1ull << kk);
  }
  mask[(u64)i * NW + jt] = w;
  if (jt == it) {
    csArr[i] = w & ((1ull << t) - 1ull);        // self-word below bits
  } else {
    if (w & vj) {                                // valid earlier overlaps in word jt
      u32 pos = atomicAdd(&cnt[i], 1u);
      if (pos < 2u) { slotW[i * 2 + pos] = w; slotI[i * 2 + pos] = (u32)jt; }
      atomicOr(&nbrw[i], 1ull << jt);            // ext words, for ovf pool build
    }
  }
  if (jt < it) {
    // emit transposed tile: row j = jt*64+t, word it; bit k = bit t of lane k's w
    tw[t] = w;
    __syncthreads();
    u64 wT = 0;
    #pragma unroll 8
    for (int k = 0; k < 64; ++k) wT |= ((tw[k] >> t) & 1ull) << k;   // LDS broadcast
    mask[(u64)j * NW + it] = wT;
  }
}

// ---------- K3: NMS + supstep, ZERO-BARRIER scan with LDS OVERFLOW POOL.
// Phase A (16 waves, TLP-hidden): coalesced slot stage; ovf boxes (cnt>2)
// pre-walk their remaining ext words' mask rows into a shared LDS pool — the
// scattered global reads happen HERE, not in the serial phase B (R11's mistake).
// Phase B (1 wave, no barriers): segments=words => ext deps final; kept lookups
// via shuffle; ovf fallback reads the LDS pool + keptL (divergence-safe, no
// shuffles); in-register ballot Gauss-Seidel within each word (R4/R11-proven).
__global__ void __launch_bounds__(1024) k_nms(const u64* __restrict__ mask,
                                              const u64* __restrict__ nbrw,
                                              const u32* __restrict__ cnt,
                                              const u64* __restrict__ slotW,
                                              const u32* __restrict__ slotI,
                                              const u64* __restrict__ csArr,
                                              const float* __restrict__ scoress,
                                              int* __restrict__ supstep) {
  __shared__ u64 csL[NB];                 // 32 KB self-word below bits
  __shared__ u64 c0L[NB];                 // 32 KB ext cache word 0
  __shared__ u64 c1L[NB];                 // 32 KB ext cache word 1
  __shared__ unsigned short i01L[NB];     //  8 KB: i0 | i1<<6 | n<<12 | ovf<<14
  __shared__ u32 povL[NB];                // 16 KB: off(16) | len(8) | gflag(31)
  __shared__ u64 poolW[POOLP];            // 24 KB overflow pool words
  __shared__ unsigned char poolIdx[POOLP];//  3 KB overflow pool word indices
  __shared__ u64 vwL[64];                 // validity words
  __shared__ u64 keptL[64];               // finalized kept words (phase-B mirror)
  __shared__ u32 poolCnt;
  int tid = threadIdx.x;
  int lane = tid & 63;
  int waveId = tid >> 6;
  if (tid == 0) poolCnt = 0;
  #pragma unroll
  for (int s4 = 0; s4 < 4; ++s4) {
    int i = tid + (s4 << 10);
    bool v = scoress[i] > COND_THRES;
    u64 vb = __ballot(v);
    if (lane == 0) vwL[waveId + (s4 << 4)] = vb;
  }
  __syncthreads();                        // poolCnt=0 visible
  // ===== phase A: coalesced slot stage + ovf pool build (TLP-hidden) =====
  #pragma unroll
  for (int s4 = 0; s4 < 4; ++s4) {
    int i = tid + (s4 << 10);
    u32 c = cnt[i];
    u64 c0 = 0, c1 = 0; u32 i0 = 0, i1 = 0;
    if (c >= 1u) { c0 = slotW[i * 2];     i0 = slotI[i * 2]; }
    if (c >= 2u) { c1 = slotW[i * 2 + 1]; i1 = slotI[i * 2 + 1]; }
    u32 n = c > 2u ? 2u : c;
    u32 ovf = c > 2u ? 1u : 0u;
    u32 pov = 0;
    if (ovf) {
      u64 t = nbrw[i] & ~(1ull << i0) & ~(1ull << i1);
      u32 len = (u32)__popcll(t);
      u32 off = atomicAdd(&poolCnt, len);
      if (off + len <= (u32)POOLP) {
        u32 k = 0;
        while (t) {
          int w = __builtin_ctzll(t);
          t &= t - 1;
          poolW[off + k] = mask[(u64)i * NW + w];   // scattered, TLP-hidden here
          poolIdx[off + k] = (unsigned char)w;
          ++k;
        }
        pov = off | (len << 16);
      } else {
        pov = 0x80000000u;                // pool full (practically unreachable)
      }
    }
    csL[i] = csArr[i];
    c0L[i] = c0; c1L[i] = c1;
    i01L[i] = (unsigned short)(i0 | (i1 << 6) | (n << 12) | (ovf << 14));
    povL[i] = pov;
  }
  __syncthreads();
  // ===== phase B: single-wave ordered word scan, zero barriers =====
  if (tid < 64) {
    u64 keptW = 0;                 // lane w's FINAL kept word (set at segment w)
    u64 cs_c = csL[lane], c0_c = c0L[lane], c1_c = c1L[lane];
    u32 m_c = i01L[lane], p_c = povL[lane];
    u64 vws_c = vwL[0];
    for (int s = 0; s < 64; ++s) {
      // prefetch next segment (independent of kept state)
      u64 cs_n = 0, c0_n = 0, c1_n = 0, vws_n = 0; u32 m_n = 0, p_n = 0;
      if (s < 63) {
        int ip = ((s + 1) << 6) | lane;
        cs_n = csL[ip]; c0_n = c0L[ip]; c1_n = c1L[ip];
        m_n = i01L[ip]; p_n = povL[ip]; vws_n = vwL[s + 1];
      }
      int w0 = (int)(m_c & 63u), w1 = (int)((m_c >> 6) & 63u);
      u64 k0 = __shfl(keptW, w0);            // ext words FINAL (w0,w1 < s)
      u64 k1 = __shfl(keptW, w1);
      bool hk = ((c0_c & k0) | (c1_c & k1)) != 0ull;   // c0/c1 zero when unused
      if (m_c & (1u << 14)) {                // ovf fallback: LDS pool, no shuffles
        if (!(p_c & 0x80000000u)) {
          u32 off = p_c & 0xFFFFu, len = (p_c >> 16) & 0xFFu;
          for (u32 k = 0; k < len; ++k) {
            int w = poolIdx[off + k];
            hk = hk || ((poolW[off + k] & keptL[w]) != 0ull);
          }
        } else {                             // guarded global path (unreachable)
          int i = (s << 6) | lane;
          u64 t = nbrw[i];
          while (t) {
            int w = __builtin_ctzll(t);
            t &= t - 1;
            hk = hk || ((mask[(u64)i * NW + w] & keptL[w]) != 0ull);
          }
        }
      }
      // within-word Gauss-Seidel (register-only; >=1 decision/iter guaranteed)
      u64 dw = ~vws_c;                       // invalids pre-decided, not kept
      u64 kw = 0;
      bool und = (vws_c >> lane) & 1ull;
      while (true) {
        bool dec = und && ((cs_c & ~dw) == 0ull);        // no undecided earlier
        bool keep = dec && !hk && ((cs_c & kw) == 0ull); // no kept earlier
        dw |= __ballot(dec);
        kw |= __ballot(keep);
        und = und && !dec;
        if (__ballot(und) == 0ull) break;
      }
      if (lane == s) keptW = kw;             // publish word s (now final)
      if (lane == 0) keptL[s] = kw;          // LDS mirror (kw uniform via ballots)
      cs_c = cs_n; c0_c = c0_n; c1_c = c1_n; m_c = m_n; p_c = p_n; vws_c = vws_n;
    }
  }
  __syncthreads();
  // ===== supstep from LDS (kept final in keptL) =====
  #pragma unroll
  for (int s4 = 0; s4 < 4; ++s4) {
    int j = tid + (s4 << 10);
    int wj = j >> 6;
    bool valid = (vwL[wj] >> (j & 63)) & 1ull;
    int res;
    if (!valid) {
      res = -1;
    } else {
      res = j;                     // no earlier kept claimant -> j itself kept
      u32 m = i01L[j];
      int cand = 0x7FFFFFFF;
      u32 n = (m >> 12) & 3;
      if (n >= 1) {
        int w0 = (int)(m & 63u);
        u64 h = c0L[j] & keptL[w0];
        if (h) { int r = (w0 << 6) + __builtin_ctzll(h); if (r < cand) cand = r; }
      }
      if (n >= 2) {
        int w1 = (int)((m >> 6) & 63u);
        u64 h = c1L[j] & keptL[w1];
        if (h) { int r = (w1 << 6) + __builtin_ctzll(h); if (r < cand) cand = r; }
      }
      if (m & (1u << 14)) {
        u32 p = povL[j];
        if (!(p & 0x80000000u)) {
          u32 off = p & 0xFFFFu, len = (p >> 16) & 0xFFu;
          for (u32 k = 0; k < len; ++k) {     // pool ascending -> first hit = min
            int w = poolIdx[off + k];
            u64 h = poolW[off + k] & keptL[w];
            if (h) { int r = (w << 6) + __builtin_ctzll(h); if (r < cand) cand = r; break; }
          }
        } else {
          u64 t = nbrw[j];                    // ascending walk (slots re-tested, harmless)
          while (t) {
            int w = __builtin_ctzll(t);
            t &= t - 1;
            u64 h = mask[(u64)j * NW + w] & keptL[w];
            if (h) { int r = (w << 6) + __builtin_ctzll(h); if (r < cand) cand = r; break; }
          }
        }
      }
      { u64 h = csL[j] & keptL[wj];           // self-word claimants
        if (h) { int r = (wj << 6) + __builtin_ctzll(h); if (r < cand) cand = r; } }
      if (cand != 0x7FFFFFFF) res = cand;
    }
    supstep[j] = res;
  }
}

// ---------- K4: per-box merge + all outputs (verbatim round-7, best-measured).
__global__ void __launch_bounds__(64) k_merge(
    const u64* __restrict__ mask, const int* __restrict__ supstep,
    const float* __restrict__ box9s, const float* __restrict__ scoress,
    const int* __restrict__ labelss,
    const float* __restrict__ w1, const float* __restrict__ b1,
    const float* __restrict__ w2, const float* __restrict__ b2,
    const float* __restrict__ w3, const float* __restrict__ b3,
    float* __restrict__ out) {
  #pragma clang fp contract(off)
  __shared__ int candList[MM];
  __shared__ float ob[MM][7];
  __shared__ float h1[7][HH];
  __shared__ float h2[7][HH];
  __shared__ float res[7];
  int i = blockIdx.x;
  int t = threadIdx.x;
  bool active = (supstep[i] == i);
  u64 wq = 0;
  int cnt = 0;
  if (active) {
    u64 w = mask[(u64)i * NW + t];
    while (w) {
      int b = __builtin_ctzll(w);
      w &= w - 1;
      int j = (t << 6) | b;
      if (supstep[j] >= i) { wq |= (1ull << b); cnt++; }
    }
  }
  int incl = cnt;
  #pragma unroll
  for (int off = 1; off < 64; off <<= 1) {
    int v = __shfl_up(incl, off);
    if (t >= off) incl += v;
  }
  int excl = incl - cnt;
  int count = __shfl(incl, 63);
  bool merged = active && (count > 1);
  if (merged && wq) {
    int pos = excl;
    u64 ww = wq;
    while (ww && pos < MM) {
      int b = __builtin_ctzll(ww);
      ww &= ww - 1;
      candList[pos++] = (t << 6) | b;
    }
  }
  __syncthreads();
  if (merged) {
    int nc = count < MM ? count : MM;
    if (t < MM) {
      if (t < nc) {
        int j = candList[t];
        #pragma unroll
        for (int f = 0; f < 7; ++f) ob[t][f] = box9s[j * 9 + f];
      } else {
        #pragma unroll
        for (int f = 0; f < 7; ++f) ob[t][f] = 0.0f;
      }
    }
    __syncthreads();
    for (int o = t; o < 7 * HH; o += 64) {
      int f = o >> 4, hh = o & 15;
      float acc = b1[hh];
      #pragma unroll
      for (int m = 0; m < MM; ++m) acc += ob[m][f] * w1[m * HH + hh];
      h1[f][hh] = fmaxf(acc, 0.0f);
    }
    __syncthreads();
    for (int o = t; o < 7 * HH; o += 64) {
      int f = o >> 4, oo = o & 15;
      float acc = b2[oo];
      #pragma unroll
      for (int k = 0; k < HH; ++k) acc += h1[f][k] * w2[k * HH + oo];
      h2[f][oo] = fmaxf(acc, 0.0f);
    }
    __syncthreads();
    if (t < 7) {
      float acc = b3[0];
      #pragma unroll
      for (int k = 0; k < HH; ++k) acc += h2[t][k] * w3[k];
      if (t >= 3 && t < 6) acc = fmaxf(acc, 1e-5f);
      res[t] = acc;
    }
    __syncthreads();
  }
  if (t < 9) {
    float v = box9s[i * 9 + t];
    if (merged && t < 7) v = res[t];
    out[i * 9 + t] = v;
  }
  if (t == 0) {
    out[NB * 9 + i]          = scoress[i];
    out[NB * 9 + NB + i]     = (float)labelss[i];
    out[NB * 9 + 2 * NB + i] = active ? 1.0f : 0.0f;
  }
}

extern "C" void kernel_launch(void* const* d_in, const int* in_sizes, int n_in,
                              void* d_out, int out_size, void* d_ws, size_t ws_size,
                              hipStream_t stream) {
  const float* boxes9 = (const float*)d_in[0];
  const float* scores = (const float*)d_in[1];
  const int*   labels = (const int*)d_in[2];
  const float* w1 = (const float*)d_in[3];
  const float* b1 = (const float*)d_in[4];
  const float* w2 = (const float*)d_in[5];
  const float* b2 = (const float*)d_in[6];
  const float* w3 = (const float*)d_in[7];
  const float* b3 = (const float*)d_in[8];
  char* ws = (char*)d_ws;
  u64*    mask    = (u64*)(ws + WS_MASK);
  float*  box9s   = (float*)(ws + WS_BOX9S);
  float4* bevs    = (float4*)(ws + WS_BEVS);
  float*  scoress = (float*)(ws + WS_SCORES);
  int*    labelss = (int*)(ws + WS_LABELS);
  u64*    nbrw    = (u64*)(ws + WS_NBRW);
  int*    supstep = (int*)(ws + WS_SUPSTEP);
  u32*    cnt     = (u32*)(ws + WS_CNT);
  u64*    slotW   = (u64*)(ws + WS_SLOTW);
  u32*    slotI   = (u32*)(ws + WS_SLOTI);
  u64*    csArr   = (u64*)(ws + WS_CSARR);
  float*  out     = (float*)d_out;

  hipLaunchKernelGGL(k_prep,  dim3(256),   dim3(256),  0, stream,
                     scores, boxes9, labels, box9s, bevs, scoress, labelss, nbrw, cnt);
  hipLaunchKernelGGL(k_mask,  dim3(NTILE), dim3(64),   0, stream,
                     bevs, labelss, scoress, mask, nbrw, cnt, slotW, slotI, csArr);
  hipLaunchKernelGGL(k_nms,   dim3(1),     dim3(1024), 0, stream,
                     mask, nbrw, cnt, slotW, slotI, csArr, scoress, supstep);
  hipLaunchKernelGGL(k_merge, dim3(NB),    dim3(64),   0, stream,
                     mask, supstep, box9s, scoress, labelss,
                     w1, b1, w2, b2, w3, b3, out);
}

// Round 14
// 110.904 us; speedup vs baseline: 1.1159x; 1.1159x over previous
//
#include <hip/hip_runtime.h>
#include <cstdint>

typedef unsigned long long u64;
typedef unsigned int u32;

#define NB 4096
#define NW 64            // 64-bit words per mask row
#define MM 20
#define HH 16
#define COND_THRES 0.2f
#define IOU_THRES 0.3f
#define PI_F  3.14159265358979323846f
#define PI4_F 0.78539816339744830962f

// ---- workspace layout (bytes) ----
#define WS_KEPT    0                           // u64[64] (unused now, kept for layout stability)
#define WS_MASK    32768                       // u64[NB*NW] = 2 MiB
#define WS_BOX9S   (WS_MASK + NB*NW*8)         // float[NB*9]
#define WS_BEVS    (WS_BOX9S + NB*9*4)         // float4[NB]
#define WS_SCORES  (WS_BEVS + NB*16)           // float[NB]
#define WS_LABELS  (WS_SCORES + NB*4)          // int[NB]
#define WS_NBRW    (WS_LABELS + NB*4)          // u64[NB]
#define WS_SUPSTEP (WS_NBRW + NB*8)            // int[NB]

__device__ __forceinline__ u64 sort_key(float s, int i) {
  u32 sb = (s > COND_THRES) ? __float_as_uint(s) : 0u;
  return ((u64)(sb ^ 0xFFFFFFFFu) << 12) | (u64)i;
}

// ---------- K1: fused counting-rank + scatter + BEV (verbatim round-7, best-measured).
__global__ void __launch_bounds__(256) k_prep(const float* __restrict__ scores,
                                              const float* __restrict__ boxes9,
                                              const int* __restrict__ labels,
                                              float* __restrict__ box9s, float4* __restrict__ bevs,
                                              float* __restrict__ scoress, int* __restrict__ labelss,
                                              u64* __restrict__ nbrw) {
  #pragma clang fp contract(off)
  __shared__ u64 keys[NB];        // 32 KB
  __shared__ u32 part[16][16];
  int tid = threadIdx.x;
  for (int k = tid; k < NB; k += 256) keys[k] = sort_key(scores[k], k);
  __syncthreads();
  int bl = tid & 15;              // box-local 0..15
  int ch = tid >> 4;              // chunk 0..15 (256 keys each)
  u64 ki = keys[blockIdx.x * 16 + bl];
  int c = 0;
  #pragma unroll 16
  for (int t = 0; t < 256; ++t) c += (keys[(ch << 8) + t] < ki) ? 1 : 0;  // LDS broadcast
  part[bl][ch] = (u32)c;
  __syncthreads();
  if (tid < 16) {
    int i = blockIdx.x * 16 + tid;
    int r = 0;
    #pragma unroll
    for (int q = 0; q < 16; ++q) r += (int)part[tid][q];
    nbrw[i] = 0;
    float b[9];
    #pragma unroll
    for (int f = 0; f < 9; ++f) b[f] = boxes9[i * 9 + f];
    #pragma unroll
    for (int f = 0; f < 9; ++f) box9s[r * 9 + f] = b[f];
    float ang = b[6] - floorf(b[6] / PI_F + 0.5f) * PI_F;
    bool sw = fabsf(ang) >= PI4_F;
    float dx = sw ? b[4] : b[3];
    float dy = sw ? b[3] : b[4];
    bevs[r] = make_float4(b[0] - dx * 0.5f, b[1] - dy * 0.5f,
                          b[0] + dx * 0.5f, b[1] + dy * 0.5f);
    scoress[r] = scores[i];
    labelss[r] = labels[i];
  }
}

// ---------- K2: pairwise over-matrix, SYMMETRIC-HALVED, triangular grid
// (verbatim round-7, best-measured).
__global__ void __launch_bounds__(64) k_mask(const float4* __restrict__ bevs,
                                             const int* __restrict__ labelss,
                                             const float* __restrict__ scoress,
                                             u64* __restrict__ mask,
                                             u64* __restrict__ nbrw) {
  #pragma clang fp contract(off)
  __shared__ float4 bj[64];
  __shared__ int lj[64];
  __shared__ u64 tw[64];
  int t = threadIdx.x;
  // triangular decode: largest it with it*(it+1)/2 <= b (float estimate + exact fix)
  int b = blockIdx.x;
  int it = (int)((sqrtf(8.0f * (float)b + 1.0f) - 1.0f) * 0.5f);
  while ((it + 1) * (it + 2) / 2 <= b) ++it;
  while (it * (it + 1) / 2 > b) --it;
  int jt = b - it * (it + 1) / 2;
  int j = jt * 64 + t;
  bj[t] = bevs[j];
  lj[t] = labelss[j];
  u64 vj = __ballot(scoress[j] > COND_THRES);   // valid mask of this j-tile
  int i = it * 64 + t;
  float4 a = bevs[i];
  int la = labelss[i];
  float area_a = (a.z - a.x) * (a.w - a.y);
  __syncthreads();
  u64 w = 0;
  #pragma unroll 8
  for (int kk = 0; kk < 64; ++kk) {
    float4 bb = bj[kk];
    float xmin = fmaxf(a.x, bb.x), ymin = fmaxf(a.y, bb.y);
    float xmax = fminf(a.z, bb.z), ymax = fminf(a.w, bb.w);
    float inter = fmaxf(xmax - xmin, 0.0f) * fmaxf(ymax - ymin, 0.0f);
    float area_b = (bb.z - bb.x) * (bb.w - bb.y);
    float iou = inter / fmaxf(area_a + area_b - inter, 1e-6f);
    if ((iou > IOU_THRES) && (la == lj[kk])) w |= (1ull << kk);
  }
  mask[(u64)i * NW + jt] = w;
  {
    u64 below = (jt < it) ? ~0ull : ((1ull << t) - 1ull);
    if (w & vj & below) atomicOr(&nbrw[i], 1ull << jt);
  }
  if (jt < it) {
    // emit transposed tile: row j = jt*64+t, word it; bit k = bit t of lane k's w
    tw[t] = w;
    __syncthreads();
    u64 wT = 0;
    #pragma unroll 8
    for (int k = 0; k < 64; ++k) wT |= ((tw[k] >> t) & 1ull) << k;   // LDS broadcast
    mask[(u64)j * NW + it] = wT;
  }
}

// ---------- K3: greedy NMS, ORDERED SEGMENT PASSES (verbatim round-7).
__global__ void __launch_bounds__(1024) k_nms(const u64* __restrict__ mask,
                                              const u64* __restrict__ nbrw,
                                              const float* __restrict__ scoress,
                                              int* __restrict__ supstep) {
  __shared__ u64 decided[64], kept[64];
  __shared__ int wavePending[16];
  int tid = threadIdx.x;
  int lane = tid & 63;
  int waveId = tid >> 6;
  bool validB[4];
  #pragma unroll
  for (int s = 0; s < 4; ++s) {
    int i = tid + (s << 10);
    bool v = scoress[i] > COND_THRES;
    validB[s] = v;
    u64 vw = __ballot(v);
    if (lane == 0) {
      decided[waveId + (s << 4)] = ~vw;   // invalids pre-decided, not kept
      kept[waveId + (s << 4)] = 0;
    }
  }
  // register cache: up to 2 masked neighbor words per owned box
  u64 cw0[4], cw1[4];
  u32 meta[4];   // [5:0] idx0, [11:6] idx1, [13:12] n(min 2), [14] overflow
  #pragma unroll
  for (int s = 0; s < 4; ++s) {
    int i = tid + (s << 10);
    int wi = i >> 6;
    u64 bit = 1ull << (i & 63);
    u64 t = nbrw[i];
    int n = 0; u32 ovf = 0;
    u64 c0 = 0, c1 = 0; u32 i0 = 0, i1 = 0;
    while (t) {
      int w = __builtin_ctzll(t);
      t &= t - 1;
      u64 below = (w < wi) ? ~0ull : (bit - 1ull);
      u64 m = mask[(u64)i * NW + w] & below;
      if (n == 0)      { c0 = m; i0 = (u32)w; }
      else if (n == 1) { c1 = m; i1 = (u32)w; }
      else ovf = 1;
      ++n;
    }
    cw0[s] = c0; cw1[s] = c1;
    meta[s] = i0 | (i1 << 6) | ((u32)(n > 2 ? 2 : n) << 12) | (ovf << 14);
  }
  __syncthreads();
  // ===== ordered segment passes =====
  for (int s = 0; s < 4; ++s) {
    const int i = tid + (s << 10);
    const int wi = waveId + (s << 4);
    const u64 bit = 1ull << (i & 63);
    const u32 mt = meta[s];
    bool und = validB[s];
    while (true) {
      bool dec = false, keepme = false;
      if (und) {
        bool hasU = false, hasK = false;
        if (!(mt & (1u << 14))) {
          int n = (mt >> 12) & 3;
          if (n >= 1) {
            int w = mt & 63;
            u64 dw = decided[w], kw = kept[w];
            hasU = (cw0[s] & ~dw) != 0ull;
            hasK = (cw0[s] & kw) != 0ull;
          }
          if (n >= 2) {
            int w = (mt >> 6) & 63;
            u64 dw = decided[w], kw = kept[w];
            hasU = hasU || ((cw1[s] & ~dw) != 0ull);
            hasK = hasK || ((cw1[s] & kw) != 0ull);
          }
        } else {
          u64 t = nbrw[i];
          while (t) {
            int w = __builtin_ctzll(t);
            t &= t - 1;
            u64 below = (w < wi) ? ~0ull : (bit - 1ull);
            u64 m = mask[(u64)i * NW + w] & below;
            hasU = hasU || ((m & ~decided[w]) != 0ull);
            hasK = hasK || ((m & kept[w]) != 0ull);
          }
        }
        dec = !hasU;
        keepme = !hasK;
      }
      u64 b_nd = __ballot(dec);
      u64 b_nk = __ballot(dec && keepme);
      bool pend = und && !dec;
      u64 pw = __ballot(pend);
      if (lane == 0) {
        decided[wi] |= b_nd;               // wave exclusively owns word wi
        kept[wi] |= b_nk;
        wavePending[waveId] = (pw != 0ull) ? 1 : 0;
      }
      und = pend;
      __syncthreads();
      int any = 0;
      #pragma unroll
      for (int w = 0; w < 16; ++w) any |= wavePending[w];   // LDS broadcast
      if (!any) break;
    }
  }
  // ===== supstep from cache (kept[] final in LDS) =====
  #pragma unroll
  for (int s = 0; s < 4; ++s) {
    int j = tid + (s << 10);
    int res;
    if (!validB[s]) {
      res = -1;
    } else {
      res = j;                       // no earlier kept claimant -> j itself kept
      u32 mt = meta[s];
      if (!(mt & (1u << 14))) {
        int n = (mt >> 12) & 3;
        if (n >= 1) {
          int w0 = mt & 63;
          u64 m0 = cw0[s] & kept[w0];
          if (m0) {
            res = (w0 << 6) + __builtin_ctzll(m0);          // min word, min bit
          } else if (n >= 2) {
            int w1 = (mt >> 6) & 63;
            u64 m1 = cw1[s] & kept[w1];
            if (m1) res = (w1 << 6) + __builtin_ctzll(m1);
          }
        }
      } else {
        // rare (>2 words): global re-scan, words ascending -> min claimant
        int wj = j >> 6;
        u64 bitbelow = (1ull << (j & 63)) - 1ull;
        u64 t = nbrw[j];
        while (t) {
          int w = __builtin_ctzll(t);
          t &= t - 1;
          u64 m = mask[(u64)j * NW + w] & kept[w];
          if (w == wj) m &= bitbelow;
          if (m) { res = (w << 6) + __builtin_ctzll(m); break; }
        }
      }
    }
    supstep[j] = res;
  }
}

// ---------- K4: per-box merge + all outputs (verbatim round-7).
__global__ void __launch_bounds__(64) k_merge(
    const u64* __restrict__ mask, const int* __restrict__ supstep,
    const float* __restrict__ box9s, const float* __restrict__ scoress,
    const int* __restrict__ labelss,
    const float* __restrict__ w1, const float* __restrict__ b1,
    const float* __restrict__ w2, const float* __restrict__ b2,
    const float* __restrict__ w3, const float* __restrict__ b3,
    float* __restrict__ out) {
  #pragma clang fp contract(off)
  __shared__ int candList[MM];
  __shared__ float ob[MM][7];
  __shared__ float h1[7][HH];
  __shared__ float h2[7][HH];
  __shared__ float res[7];
  int i = blockIdx.x;
  int t = threadIdx.x;
  bool active = (supstep[i] == i);
  u64 wq = 0;
  int cnt = 0;
  if (active) {
    u64 w = mask[(u64)i * NW + t];
    while (w) {
      int b = __builtin_ctzll(w);
      w &= w - 1;
      int j = (t << 6) | b;
      if (supstep[j] >= i) { wq |= (1ull << b); cnt++; }
    }
  }
  int incl = cnt;
  #pragma unroll
  for (int off = 1; off < 64; off <<= 1) {
    int v = __shfl_up(incl, off);
    if (t >= off) incl += v;
  }
  int excl = incl - cnt;
  int count = __shfl(incl, 63);
  bool merged = active && (count > 1);
  if (merged && wq) {
    int pos = excl;
    u64 ww = wq;
    while (ww && pos < MM) {
      int b = __builtin_ctzll(ww);
      ww &= ww - 1;
      candList[pos++] = (t << 6) | b;
    }
  }
  __syncthreads();
  if (merged) {
    int nc = count < MM ? count : MM;
    if (t < MM) {
      if (t < nc) {
        int j = candList[t];
        #pragma unroll
        for (int f = 0; f < 7; ++f) ob[t][f] = box9s[j * 9 + f];
      } else {
        #pragma unroll
        for (int f = 0; f < 7; ++f) ob[t][f] = 0.0f;
      }
    }
    __syncthreads();
    for (int o = t; o < 7 * HH; o += 64) {
      int f = o >> 4, hh = o & 15;
      float acc = b1[hh];
      #pragma unroll
      for (int m = 0; m < MM; ++m) acc += ob[m][f] * w1[m * HH + hh];
      h1[f][hh] = fmaxf(acc, 0.0f);
    }
    __syncthreads();
    for (int o = t; o < 7 * HH; o += 64) {
      int f = o >> 4, oo = o & 15;
      float acc = b2[oo];
      #pragma unroll
      for (int k = 0; k < HH; ++k) acc += h1[f][k] * w2[k * HH + oo];
      h2[f][oo] = fmaxf(acc, 0.0f);
    }
    __syncthreads();
    if (t < 7) {
      float acc = b3[0];
      #pragma unroll
      for (int k = 0; k < HH; ++k) acc += h2[t][k] * w3[k];
      if (t >= 3 && t < 6) acc = fmaxf(acc, 1e-5f);
      res[t] = acc;
    }
    __syncthreads();
  }
  if (t < 9) {
    float v = box9s[i * 9 + t];
    if (merged && t < 7) v = res[t];
    out[i * 9 + t] = v;
  }
  if (t == 0) {
    out[NB * 9 + i]          = scoress[i];
    out[NB * 9 + NB + i]     = (float)labelss[i];
    out[NB * 9 + 2 * NB + i] = active ? 1.0f : 0.0f;
  }
}

extern "C" void kernel_launch(void* const* d_in, const int* in_sizes, int n_in,
                              void* d_out, int out_size, void* d_ws, size_t ws_size,
                              hipStream_t stream) {
  const float* boxes9 = (const float*)d_in[0];
  const float* scores = (const float*)d_in[1];
  const int*   labels = (const int*)d_in[2];
  const float* w1 = (const float*)d_in[3];
  const float* b1 = (const float*)d_in[4];
  const float* w2 = (const float*)d_in[5];
  const float* b2 = (const float*)d_in[6];
  const float* w3 = (const float*)d_in[7];
  const float* b3 = (const float*)d_in[8];
  char* ws = (char*)d_ws;
  u64*    mask    = (u64*)(ws + WS_MASK);
  float*  box9s   = (float*)(ws + WS_BOX9S);
  float4* bevs    = (float4*)(ws + WS_BEVS);
  float*  scoress = (float*)(ws + WS_SCORES);
  int*    labelss = (int*)(ws + WS_LABELS);
  u64*    nbrw    = (u64*)(ws + WS_NBRW);
  int*    supstep = (int*)(ws + WS_SUPSTEP);
  float*  out     = (float*)d_out;

  hipLaunchKernelGGL(k_prep,  dim3(256),  dim3(256),  0, stream,
                     scores, boxes9, labels, box9s, bevs, scoress, labelss, nbrw);
  hipLaunchKernelGGL(k_mask,  dim3(2080), dim3(64),   0, stream,
                     bevs, labelss, scoress, mask, nbrw);
  hipLaunchKernelGGL(k_nms,   dim3(1),    dim3(1024), 0, stream,
                     mask, nbrw, scoress, supstep);
  hipLaunchKernelGGL(k_merge, dim3(NB),   dim3(64),   0, stream,
                     mask, supstep, box9s, scoress, labelss,
                     w1, b1, w2, b2, w3, b3, out);
}